// Round 7
// baseline (24.306 us; speedup 1.0000x reference)
//
#include <hip/hip_runtime.h>
#include <math.h>

#define NS 21          // percept rows (index 0 unused, idx in [1,20])
#define NPAIR (NS*NS)  // 441 precomputed pairs

typedef int   int4v   __attribute__((ext_vector_type(4)));
typedef float float4v __attribute__((ext_vector_type(4)));

#define LOG2E 1.4426950408889634f
#define LN2   0.6931471805599453f

// x >= 0 ; 0^r -> exp2(r * -inf) = 0, correct for r > 0
__device__ __forceinline__ float fast_pow(float x, float r) {
    return __builtin_amdgcn_exp2f(r * __builtin_amdgcn_logf(x));
}

__global__ __launch_bounds__(256) void rank_rt_kernel(
    const int*   __restrict__ idx,      // (nrows, 5)
    const float* __restrict__ percept,  // (21, 3)
    const float* __restrict__ w,        // (3,)
    const float* __restrict__ rho_p,
    const float* __restrict__ beta_p,
    const float* __restrict__ tau_p,
    const float* __restrict__ gamma_p,
    const float* __restrict__ upper_p,
    const float* __restrict__ mid_p,
    const float* __restrict__ rate_p,
    float* __restrict__ out,            // p: nrows*4, then rt: nrows
    int nrows)
{
    __shared__ float s_tab[NPAIR];      // s(q,r)          — 4B entries: 32 start banks
    __shared__ float t_tab[NPAIR];      // s*log(s)(q,r)

    const int q = blockIdx.x * 256 + threadIdx.x;   // one quad (4 rows) per thread
    const int quads = (nrows + 3) >> 2;
    const bool full = (q < quads) && ((q + 1) * 4 <= nrows);

    // ---- issue idx loads FIRST: HBM latency hides under the table build ----
    int4v a0, a1, a2, a3, a4;
    if (full) {
        const int4v* ip = reinterpret_cast<const int4v*>(idx + (size_t)q * 20);
        a0 = ip[0]; a1 = ip[1]; a2 = ip[2]; a3 = ip[3]; a4 = ip[4];
    }

    // ---- per-block table build: fast-math pow, ~2 entries/thread ----
    {
        const float rho   = rho_p[0];
        const float beta  = beta_p[0];
        const float tau   = tau_p[0];
        const float gamma = gamma_p[0];
        const float w0 = w[0], w1 = w[1], w2 = w[2];
        const float inv_rho = 1.0f / rho;
        for (int e = threadIdx.x; e < NPAIR; e += 256) {
            int qq = e / NS;
            int rr = e - qq * NS;
            float dx = fabsf(percept[qq * 3 + 0] - percept[rr * 3 + 0]);
            float dy = fabsf(percept[qq * 3 + 1] - percept[rr * 3 + 1]);
            float dz = fabsf(percept[qq * 3 + 2] - percept[rr * 3 + 2]);
            float acc = w0 * fast_pow(dx, rho) + w1 * fast_pow(dy, rho)
                      + w2 * fast_pow(dz, rho);
            float d = fast_pow(acc, inv_rho);
            float s = __builtin_amdgcn_exp2f(-beta * LOG2E * fast_pow(d, tau)) + gamma;
            s_tab[e] = s;
            t_tab[e] = s * (LN2 * __builtin_amdgcn_logf(s));
        }
    }
    const float upper = upper_p[0];
    const float mid   = mid_p[0];
    const float rate  = rate_p[0];
    __syncthreads();

    if (q >= quads) return;

    if (full) {
        const int v[20] = { a0.x, a0.y, a0.z, a0.w,
                            a1.x, a1.y, a1.z, a1.w,
                            a2.x, a2.y, a2.z, a2.w,
                            a3.x, a3.y, a3.z, a3.w,
                            a4.x, a4.y, a4.z, a4.w };
        const size_t row0 = (size_t)q * 4;
        float rt_arr[4];
        #pragma unroll
        for (int k = 0; k < 4; ++k) {
            const int qb = v[5 * k] * NS;
            const int i0 = qb + v[5 * k + 1];
            const int i1 = qb + v[5 * k + 2];
            const int i2 = qb + v[5 * k + 3];
            const int i3 = qb + v[5 * k + 4];
            float s0 = s_tab[i0], s1 = s_tab[i1], s2 = s_tab[i2], s3 = s_tab[i3];
            float t0 = t_tab[i0], t1 = t_tab[i1], t2 = t_tab[i2], t3 = t_tab[i3];

            float S = (s0 + s1) + (s2 + s3);
            float T = (t0 + t1) + (t2 + t3);
            float invS = __builtin_amdgcn_rcpf(S);

            float ent = LN2 * __builtin_amdgcn_logf(S) - T * invS;
            float z   = -rate * (ent - mid);
            rt_arr[k] = upper * __builtin_amdgcn_rcpf(
                            1.0f + __builtin_amdgcn_exp2f(z * LOG2E));

            float4v p;
            p.x = s0 * invS;
            p.y = s1 * invS;
            p.z = s2 * invS;
            p.w = s3 * invS;
            *reinterpret_cast<float4v*>(out + (row0 + k) * 4) = p;
        }
        float4v rt4;
        rt4.x = rt_arr[0]; rt4.y = rt_arr[1]; rt4.z = rt_arr[2]; rt4.w = rt_arr[3];
        *reinterpret_cast<float4v*>(out + (size_t)nrows * 4 + row0) = rt4;
    } else {
        // tail quad (nrows % 4 != 0): scalar path
        for (size_t row = (size_t)q * 4; row < (size_t)nrows; ++row) {
            const size_t base = row * 5;
            int qb = idx[base] * NS;
            int i0 = qb + idx[base + 1];
            int i1 = qb + idx[base + 2];
            int i2 = qb + idx[base + 3];
            int i3 = qb + idx[base + 4];
            float s0 = s_tab[i0], s1 = s_tab[i1], s2 = s_tab[i2], s3 = s_tab[i3];
            float T = (t_tab[i0] + t_tab[i1]) + (t_tab[i2] + t_tab[i3]);
            float S = (s0 + s1) + (s2 + s3);
            float invS = __builtin_amdgcn_rcpf(S);
            float ent = LN2 * __builtin_amdgcn_logf(S) - T * invS;
            float z   = -rate * (ent - mid);
            float rt  = upper * __builtin_amdgcn_rcpf(
                            1.0f + __builtin_amdgcn_exp2f(z * LOG2E));
            out[row * 4 + 0] = s0 * invS;
            out[row * 4 + 1] = s1 * invS;
            out[row * 4 + 2] = s2 * invS;
            out[row * 4 + 3] = s3 * invS;
            out[(size_t)nrows * 4 + row] = rt;
        }
    }
}

extern "C" void kernel_launch(void* const* d_in, const int* in_sizes, int n_in,
                              void* d_out, int out_size, void* d_ws, size_t ws_size,
                              hipStream_t stream) {
    const int*   idx     = (const int*)  d_in[0];
    const float* percept = (const float*)d_in[1];
    const float* w       = (const float*)d_in[2];
    const float* rho     = (const float*)d_in[3];
    const float* beta    = (const float*)d_in[4];
    const float* tau     = (const float*)d_in[5];
    const float* gamma   = (const float*)d_in[6];
    const float* upper   = (const float*)d_in[7];
    const float* mid     = (const float*)d_in[8];
    const float* rate    = (const float*)d_in[9];
    float* out = (float*)d_out;

    const int nrows = in_sizes[0] / 5;
    const int quads = (nrows + 3) / 4;      // 1 quad (4 rows) per thread
    const int block = 256;
    const int grid  = (quads + block - 1) / block;   // 2048 blocks at B=2M

    rank_rt_kernel<<<grid, block, 0, stream>>>(
        idx, percept, w, rho, beta, tau, gamma, upper, mid, rate, out, nrows);
}

// Round 8
// 24.061 us; speedup vs baseline: 1.0102x; 1.0102x over previous
//
#include <hip/hip_runtime.h>
#include <math.h>

#define NS 21          // percept rows (index 0 unused, idx in [1,20])
#define NPAIR (NS*NS)  // 441 precomputed pairs

typedef int   int4v   __attribute__((ext_vector_type(4)));
typedef float float4v __attribute__((ext_vector_type(4)));
typedef float float2v __attribute__((ext_vector_type(2)));

#define LOG2E 1.4426950408889634f
#define LN2   0.6931471805599453f

// x >= 0 ; 0^r -> exp2(r * -inf) = 0, correct for r > 0
__device__ __forceinline__ float fast_pow(float x, float r) {
    return __builtin_amdgcn_exp2f(r * __builtin_amdgcn_logf(x));
}

__global__ __launch_bounds__(256) void rank_rt_kernel(
    const int*   __restrict__ idx,      // (nrows, 5)
    const float* __restrict__ percept,  // (21, 3)
    const float* __restrict__ w,        // (3,)
    const float* __restrict__ rho_p,
    const float* __restrict__ beta_p,
    const float* __restrict__ tau_p,
    const float* __restrict__ gamma_p,
    const float* __restrict__ upper_p,
    const float* __restrict__ mid_p,
    const float* __restrict__ rate_p,
    float* __restrict__ out,            // p: nrows*4, then rt: nrows
    int nrows)
{
    __shared__ float2v tab[NPAIR];      // {s, s*log(s)} per (q,r) — b64 gathers

    const int q = blockIdx.x * 256 + threadIdx.x;   // one quad (4 rows) per thread
    const int quads = (nrows + 3) >> 2;
    const bool full = (q < quads) && ((q + 1) * 4 <= nrows);

    // ---- issue idx loads FIRST: HBM latency hides under the table build ----
    int4v a0, a1, a2, a3, a4;
    if (full) {
        const int4v* ip = reinterpret_cast<const int4v*>(idx + (size_t)q * 20);
        a0 = ip[0]; a1 = ip[1]; a2 = ip[2]; a3 = ip[3]; a4 = ip[4];
    }

    // ---- per-block table build: fast-math pow, ~2 entries/thread ----
    {
        const float rho   = rho_p[0];
        const float beta  = beta_p[0];
        const float tau   = tau_p[0];
        const float gamma = gamma_p[0];
        const float w0 = w[0], w1 = w[1], w2 = w[2];
        const float inv_rho = 1.0f / rho;
        for (int e = threadIdx.x; e < NPAIR; e += 256) {
            int qq = e / NS;
            int rr = e - qq * NS;
            float dx = fabsf(percept[qq * 3 + 0] - percept[rr * 3 + 0]);
            float dy = fabsf(percept[qq * 3 + 1] - percept[rr * 3 + 1]);
            float dz = fabsf(percept[qq * 3 + 2] - percept[rr * 3 + 2]);
            float acc = w0 * fast_pow(dx, rho) + w1 * fast_pow(dy, rho)
                      + w2 * fast_pow(dz, rho);
            float d = fast_pow(acc, inv_rho);
            float s = __builtin_amdgcn_exp2f(-beta * LOG2E * fast_pow(d, tau)) + gamma;
            float2v o;
            o.x = s;
            o.y = s * (LN2 * __builtin_amdgcn_logf(s));
            tab[e] = o;
        }
    }
    const float upper = upper_p[0];
    const float mid   = mid_p[0];
    const float rate  = rate_p[0];
    __syncthreads();

    if (q >= quads) return;

    if (full) {
        const int v[20] = { a0.x, a0.y, a0.z, a0.w,
                            a1.x, a1.y, a1.z, a1.w,
                            a2.x, a2.y, a2.z, a2.w,
                            a3.x, a3.y, a3.z, a3.w,
                            a4.x, a4.y, a4.z, a4.w };
        const size_t row0 = (size_t)q * 4;
        float rt_arr[4];
        #pragma unroll
        for (int k = 0; k < 4; ++k) {
            const int qb = v[5 * k] * NS;
            float2v e0 = tab[qb + v[5 * k + 1]];
            float2v e1 = tab[qb + v[5 * k + 2]];
            float2v e2 = tab[qb + v[5 * k + 3]];
            float2v e3 = tab[qb + v[5 * k + 4]];

            float S = (e0.x + e1.x) + (e2.x + e3.x);
            float T = (e0.y + e1.y) + (e2.y + e3.y);
            float invS = __builtin_amdgcn_rcpf(S);

            float ent = LN2 * __builtin_amdgcn_logf(S) - T * invS;
            float z   = -rate * (ent - mid);
            rt_arr[k] = upper * __builtin_amdgcn_rcpf(
                            1.0f + __builtin_amdgcn_exp2f(z * LOG2E));

            float4v p;
            p.x = e0.x * invS;
            p.y = e1.x * invS;
            p.z = e2.x * invS;
            p.w = e3.x * invS;
            *reinterpret_cast<float4v*>(out + (row0 + k) * 4) = p;
        }
        float4v rt4;
        rt4.x = rt_arr[0]; rt4.y = rt_arr[1]; rt4.z = rt_arr[2]; rt4.w = rt_arr[3];
        *reinterpret_cast<float4v*>(out + (size_t)nrows * 4 + row0) = rt4;
    } else {
        // tail quad (nrows % 4 != 0): scalar path
        for (size_t row = (size_t)q * 4; row < (size_t)nrows; ++row) {
            const size_t base = row * 5;
            int qb = idx[base] * NS;
            float2v e0 = tab[qb + idx[base + 1]];
            float2v e1 = tab[qb + idx[base + 2]];
            float2v e2 = tab[qb + idx[base + 3]];
            float2v e3 = tab[qb + idx[base + 4]];
            float S = (e0.x + e1.x) + (e2.x + e3.x);
            float T = (e0.y + e1.y) + (e2.y + e3.y);
            float invS = __builtin_amdgcn_rcpf(S);
            float ent = LN2 * __builtin_amdgcn_logf(S) - T * invS;
            float z   = -rate * (ent - mid);
            float rt  = upper * __builtin_amdgcn_rcpf(
                            1.0f + __builtin_amdgcn_exp2f(z * LOG2E));
            out[row * 4 + 0] = e0.x * invS;
            out[row * 4 + 1] = e1.x * invS;
            out[row * 4 + 2] = e2.x * invS;
            out[row * 4 + 3] = e3.x * invS;
            out[(size_t)nrows * 4 + row] = rt;
        }
    }
}

extern "C" void kernel_launch(void* const* d_in, const int* in_sizes, int n_in,
                              void* d_out, int out_size, void* d_ws, size_t ws_size,
                              hipStream_t stream) {
    const int*   idx     = (const int*)  d_in[0];
    const float* percept = (const float*)d_in[1];
    const float* w       = (const float*)d_in[2];
    const float* rho     = (const float*)d_in[3];
    const float* beta    = (const float*)d_in[4];
    const float* tau     = (const float*)d_in[5];
    const float* gamma   = (const float*)d_in[6];
    const float* upper   = (const float*)d_in[7];
    const float* mid     = (const float*)d_in[8];
    const float* rate    = (const float*)d_in[9];
    float* out = (float*)d_out;

    const int nrows = in_sizes[0] / 5;
    const int quads = (nrows + 3) / 4;      // 1 quad (4 rows) per thread
    const int block = 256;
    const int grid  = (quads + block - 1) / block;   // 2048 blocks at B=2M

    rank_rt_kernel<<<grid, block, 0, stream>>>(
        idx, percept, w, rho, beta, tau, gamma, upper, mid, rate, out, nrows);
}

// Round 9
// 22.379 us; speedup vs baseline: 1.0861x; 1.0752x over previous
//
#include <hip/hip_runtime.h>
#include <math.h>

#define NS 21          // percept rows (index 0 unused, idx in [1,20])
#define NPAIR (NS*NS)  // 441 precomputed pairs

typedef int   int4v   __attribute__((ext_vector_type(4)));
typedef float float4v __attribute__((ext_vector_type(4)));
typedef float float2v __attribute__((ext_vector_type(2)));

#define LOG2E 1.4426950408889634f
#define LN2   0.6931471805599453f

// x >= 0 ; 0^r -> exp2(r * -inf) = 0, correct for r > 0
__device__ __forceinline__ float fast_pow(float x, float r) {
    return __builtin_amdgcn_exp2f(r * __builtin_amdgcn_logf(x));
}

__global__ __launch_bounds__(256) void rank_rt_kernel(
    const int*   __restrict__ idx,      // (nrows, 5)
    const float* __restrict__ percept,  // (21, 3)
    const float* __restrict__ w,        // (3,)
    const float* __restrict__ rho_p,
    const float* __restrict__ beta_p,
    const float* __restrict__ tau_p,
    const float* __restrict__ gamma_p,
    const float* __restrict__ upper_p,
    const float* __restrict__ mid_p,
    const float* __restrict__ rate_p,
    float* __restrict__ out,            // p: nrows*4, then rt: nrows
    int nrows)
{
    __shared__ float2v tab[NPAIR];      // {s, s*log(s)} per (q,r)

    // ---- per-block table build: fast-math pow, ~2 entries/thread ----
    {
        const float rho   = rho_p[0];
        const float beta  = beta_p[0];
        const float tau   = tau_p[0];
        const float gamma = gamma_p[0];
        const float w0 = w[0], w1 = w[1], w2 = w[2];
        const float inv_rho = 1.0f / rho;
        for (int e = threadIdx.x; e < NPAIR; e += 256) {
            int q = e / NS;
            int r = e - q * NS;
            float dx = fabsf(percept[q * 3 + 0] - percept[r * 3 + 0]);
            float dy = fabsf(percept[q * 3 + 1] - percept[r * 3 + 1]);
            float dz = fabsf(percept[q * 3 + 2] - percept[r * 3 + 2]);
            float acc = w0 * fast_pow(dx, rho) + w1 * fast_pow(dy, rho)
                      + w2 * fast_pow(dz, rho);
            float d = fast_pow(acc, inv_rho);
            float s = __builtin_amdgcn_exp2f(-beta * LOG2E * fast_pow(d, tau)) + gamma;
            float2v o;
            o.x = s;
            o.y = s * (LN2 * __builtin_amdgcn_logf(s));
            tab[e] = o;
        }
    }
    const float upper = upper_p[0];
    const float mid   = mid_p[0];
    const float rate  = rate_p[0];
    __syncthreads();

    const int q = blockIdx.x * 256 + threadIdx.x;   // one quad (4 rows) per thread
    const int quads = (nrows + 3) >> 2;
    if (q >= quads) return;

    if ((q + 1) * 4 <= nrows) {
        // 4 rows: 20 ints = 5 x int4, all issued upfront
        const int4v* ip = reinterpret_cast<const int4v*>(idx + (size_t)q * 20);
        int4v a0 = ip[0], a1 = ip[1], a2 = ip[2], a3 = ip[3], a4 = ip[4];
        const int v[20] = { a0.x, a0.y, a0.z, a0.w,
                            a1.x, a1.y, a1.z, a1.w,
                            a2.x, a2.y, a2.z, a2.w,
                            a3.x, a3.y, a3.z, a3.w,
                            a4.x, a4.y, a4.z, a4.w };
        const size_t row0 = (size_t)q * 4;
        float rt_arr[4];
        #pragma unroll
        for (int k = 0; k < 4; ++k) {
            const int qb = v[5 * k] * NS;
            float2v e0 = tab[qb + v[5 * k + 1]];
            float2v e1 = tab[qb + v[5 * k + 2]];
            float2v e2 = tab[qb + v[5 * k + 3]];
            float2v e3 = tab[qb + v[5 * k + 4]];

            float S = (e0.x + e1.x) + (e2.x + e3.x);
            float T = (e0.y + e1.y) + (e2.y + e3.y);
            float invS = __builtin_amdgcn_rcpf(S);

            float ent = LN2 * __builtin_amdgcn_logf(S) - T * invS;
            float z   = -rate * (ent - mid);
            rt_arr[k] = upper * __builtin_amdgcn_rcpf(
                            1.0f + __builtin_amdgcn_exp2f(z * LOG2E));

            float4v p;
            p.x = e0.x * invS;
            p.y = e1.x * invS;
            p.z = e2.x * invS;
            p.w = e3.x * invS;
            *reinterpret_cast<float4v*>(out + (row0 + k) * 4) = p;
        }
        float4v rt4;
        rt4.x = rt_arr[0]; rt4.y = rt_arr[1]; rt4.z = rt_arr[2]; rt4.w = rt_arr[3];
        *reinterpret_cast<float4v*>(out + (size_t)nrows * 4 + row0) = rt4;
    } else {
        // tail quad (nrows % 4 != 0): scalar path
        for (size_t row = (size_t)q * 4; row < (size_t)nrows; ++row) {
            const size_t base = row * 5;
            int qb = idx[base] * NS;
            float2v e0 = tab[qb + idx[base + 1]];
            float2v e1 = tab[qb + idx[base + 2]];
            float2v e2 = tab[qb + idx[base + 3]];
            float2v e3 = tab[qb + idx[base + 4]];
            float S = (e0.x + e1.x) + (e2.x + e3.x);
            float T = (e0.y + e1.y) + (e2.y + e3.y);
            float invS = __builtin_amdgcn_rcpf(S);
            float ent = LN2 * __builtin_amdgcn_logf(S) - T * invS;
            float z   = -rate * (ent - mid);
            float rt  = upper * __builtin_amdgcn_rcpf(
                            1.0f + __builtin_amdgcn_exp2f(z * LOG2E));
            out[row * 4 + 0] = e0.x * invS;
            out[row * 4 + 1] = e1.x * invS;
            out[row * 4 + 2] = e2.x * invS;
            out[row * 4 + 3] = e3.x * invS;
            out[(size_t)nrows * 4 + row] = rt;
        }
    }
}

extern "C" void kernel_launch(void* const* d_in, const int* in_sizes, int n_in,
                              void* d_out, int out_size, void* d_ws, size_t ws_size,
                              hipStream_t stream) {
    const int*   idx     = (const int*)  d_in[0];
    const float* percept = (const float*)d_in[1];
    const float* w       = (const float*)d_in[2];
    const float* rho     = (const float*)d_in[3];
    const float* beta    = (const float*)d_in[4];
    const float* tau     = (const float*)d_in[5];
    const float* gamma   = (const float*)d_in[6];
    const float* upper   = (const float*)d_in[7];
    const float* mid     = (const float*)d_in[8];
    const float* rate    = (const float*)d_in[9];
    float* out = (float*)d_out;

    const int nrows = in_sizes[0] / 5;
    const int quads = (nrows + 3) / 4;      // 1 quad (4 rows) per thread
    const int block = 256;
    const int grid  = (quads + block - 1) / block;   // 2048 blocks at B=2M

    rank_rt_kernel<<<grid, block, 0, stream>>>(
        idx, percept, w, rho, beta, tau, gamma, upper, mid, rate, out, nrows);
}

// Round 10
// 20.150 us; speedup vs baseline: 1.2062x; 1.1106x over previous
//
#include <hip/hip_runtime.h>
#include <math.h>

#define NS 21          // percept rows (index 0 unused, idx in [1,20])
#define NPAIR (NS*NS)  // 441 precomputed pairs

typedef float float4v __attribute__((ext_vector_type(4)));
typedef float float2v __attribute__((ext_vector_type(2)));

#define LOG2E 1.4426950408889634f
#define LN2   0.6931471805599453f

// x >= 0 ; 0^r -> exp2(r * -inf) = 0, correct for r > 0
__device__ __forceinline__ float fast_pow(float x, float r) {
    return __builtin_amdgcn_exp2f(r * __builtin_amdgcn_logf(x));
}

__global__ __launch_bounds__(256) void rank_rt_kernel(
    const int*   __restrict__ idx,      // (nrows, 5)
    const float* __restrict__ percept,  // (21, 3)
    const float* __restrict__ w,        // (3,)
    const float* __restrict__ rho_p,
    const float* __restrict__ beta_p,
    const float* __restrict__ tau_p,
    const float* __restrict__ gamma_p,
    const float* __restrict__ upper_p,
    const float* __restrict__ mid_p,
    const float* __restrict__ rate_p,
    float* __restrict__ out,            // p: nrows*4, then rt: nrows
    int nrows)
{
    __shared__ float2v tab[NPAIR];      // {s, s*log(s)} per (q,r)

    // ---- per-block table build: fast-math pow, ~2 entries/thread ----
    {
        const float rho   = rho_p[0];
        const float beta  = beta_p[0];
        const float tau   = tau_p[0];
        const float gamma = gamma_p[0];
        const float w0 = w[0], w1 = w[1], w2 = w[2];
        const float inv_rho = 1.0f / rho;
        for (int e = threadIdx.x; e < NPAIR; e += 256) {
            int q = e / NS;
            int r = e - q * NS;
            float dx = fabsf(percept[q * 3 + 0] - percept[r * 3 + 0]);
            float dy = fabsf(percept[q * 3 + 1] - percept[r * 3 + 1]);
            float dz = fabsf(percept[q * 3 + 2] - percept[r * 3 + 2]);
            float acc = w0 * fast_pow(dx, rho) + w1 * fast_pow(dy, rho)
                      + w2 * fast_pow(dz, rho);
            float d = fast_pow(acc, inv_rho);
            float s = __builtin_amdgcn_exp2f(-beta * LOG2E * fast_pow(d, tau)) + gamma;
            float2v o;
            o.x = s;
            o.y = s * (LN2 * __builtin_amdgcn_logf(s));
            tab[e] = o;
        }
    }
    const float upper = upper_p[0];
    const float mid   = mid_p[0];
    const float rate  = rate_p[0];
    __syncthreads();

    // ---- one row per thread: lane-contiguous p (float4) and rt (dword) stores ----
    const int row = blockIdx.x * 256 + threadIdx.x;
    if (row >= nrows) return;

    const size_t base = (size_t)row * 5;
    int q  = idx[base + 0];
    int r0 = idx[base + 1];
    int r1 = idx[base + 2];
    int r2 = idx[base + 3];
    int r3 = idx[base + 4];
    const int qb = q * NS;

    float2v e0 = tab[qb + r0];
    float2v e1 = tab[qb + r1];
    float2v e2 = tab[qb + r2];
    float2v e3 = tab[qb + r3];

    float S = (e0.x + e1.x) + (e2.x + e3.x);
    float T = (e0.y + e1.y) + (e2.y + e3.y);
    float invS = __builtin_amdgcn_rcpf(S);

    float ent = LN2 * __builtin_amdgcn_logf(S) - T * invS;   // -sum p log p
    float z   = -rate * (ent - mid);
    float rt  = upper * __builtin_amdgcn_rcpf(
                    1.0f + __builtin_amdgcn_exp2f(z * LOG2E));

    float4v p;
    p.x = e0.x * invS;
    p.y = e1.x * invS;
    p.z = e2.x * invS;
    p.w = e3.x * invS;
    *reinterpret_cast<float4v*>(out + (size_t)row * 4) = p;
    out[(size_t)nrows * 4 + row] = rt;
}

extern "C" void kernel_launch(void* const* d_in, const int* in_sizes, int n_in,
                              void* d_out, int out_size, void* d_ws, size_t ws_size,
                              hipStream_t stream) {
    const int*   idx     = (const int*)  d_in[0];
    const float* percept = (const float*)d_in[1];
    const float* w       = (const float*)d_in[2];
    const float* rho     = (const float*)d_in[3];
    const float* beta    = (const float*)d_in[4];
    const float* tau     = (const float*)d_in[5];
    const float* gamma   = (const float*)d_in[6];
    const float* upper   = (const float*)d_in[7];
    const float* mid     = (const float*)d_in[8];
    const float* rate    = (const float*)d_in[9];
    float* out = (float*)d_out;

    const int nrows = in_sizes[0] / 5;
    const int block = 256;
    const int grid  = (nrows + block - 1) / block;   // 8192 blocks at B=2M

    rank_rt_kernel<<<grid, block, 0, stream>>>(
        idx, percept, w, rho, beta, tau, gamma, upper, mid, rate, out, nrows);
}

// Round 11
// 19.166 us; speedup vs baseline: 1.2682x; 1.0514x over previous
//
#include <hip/hip_runtime.h>
#include <math.h>

#define NS 21          // percept rows (index 0 unused, idx in [1,20])
#define NPAIR (NS*NS)  // 441 precomputed pairs

typedef float float4v __attribute__((ext_vector_type(4)));
typedef float float2v __attribute__((ext_vector_type(2)));

#define LOG2E 1.4426950408889634f
#define LN2   0.6931471805599453f

// x >= 0 ; 0^r -> exp2(r * -inf) = 0, correct for r > 0
__device__ __forceinline__ float fast_pow(float x, float r) {
    return __builtin_amdgcn_exp2f(r * __builtin_amdgcn_logf(x));
}

__global__ __launch_bounds__(256) void rank_rt_kernel(
    const int*   __restrict__ idx,      // (nrows, 5)
    const float* __restrict__ percept,  // (21, 3)
    const float* __restrict__ w,        // (3,)
    const float* __restrict__ rho_p,
    const float* __restrict__ beta_p,
    const float* __restrict__ tau_p,
    const float* __restrict__ gamma_p,
    const float* __restrict__ upper_p,
    const float* __restrict__ mid_p,
    const float* __restrict__ rate_p,
    float* __restrict__ out,            // p: nrows*4, then rt: nrows
    int nrows,
    int NT)                             // total threads = ceil(nrows/2)
{
    __shared__ float2v tab[NPAIR];      // {s, s*log(s)} per (q,r)

    // ---- per-block table build: fast-math pow, ~2 entries/thread ----
    {
        const float rho   = rho_p[0];
        const float beta  = beta_p[0];
        const float tau   = tau_p[0];
        const float gamma = gamma_p[0];
        const float w0 = w[0], w1 = w[1], w2 = w[2];
        const float inv_rho = 1.0f / rho;
        for (int e = threadIdx.x; e < NPAIR; e += 256) {
            int q = e / NS;
            int r = e - q * NS;
            float dx = fabsf(percept[q * 3 + 0] - percept[r * 3 + 0]);
            float dy = fabsf(percept[q * 3 + 1] - percept[r * 3 + 1]);
            float dz = fabsf(percept[q * 3 + 2] - percept[r * 3 + 2]);
            float acc = w0 * fast_pow(dx, rho) + w1 * fast_pow(dy, rho)
                      + w2 * fast_pow(dz, rho);
            float d = fast_pow(acc, inv_rho);
            float s = __builtin_amdgcn_exp2f(-beta * LOG2E * fast_pow(d, tau)) + gamma;
            float2v o;
            o.x = s;
            o.y = s * (LN2 * __builtin_amdgcn_logf(s));
            tab[e] = o;
        }
    }
    const float upper = upper_p[0];
    const float mid   = mid_p[0];
    const float rate  = rate_p[0];
    __syncthreads();

    const int t = blockIdx.x * 256 + threadIdx.x;
    const int row0 = t;                 // chunk 0: lane-contiguous
    const int row1 = t + NT;            // chunk 1: lane-contiguous
    const bool has0 = row0 < nrows;
    const bool has1 = row1 < nrows;

    // ---- issue both rows' idx loads upfront (10 independent dwords) ----
    int v0[5], v1[5];
    if (has0) {
        const size_t b = (size_t)row0 * 5;
        v0[0] = idx[b]; v0[1] = idx[b+1]; v0[2] = idx[b+2]; v0[3] = idx[b+3]; v0[4] = idx[b+4];
    }
    if (has1) {
        const size_t b = (size_t)row1 * 5;
        v1[0] = idx[b]; v1[1] = idx[b+1]; v1[2] = idx[b+2]; v1[3] = idx[b+3]; v1[4] = idx[b+4];
    }

    #pragma unroll
    for (int c = 0; c < 2; ++c) {
        const bool has = c ? has1 : has0;
        if (!has) continue;
        const int* v = c ? v1 : v0;
        const int row = c ? row1 : row0;

        const int qb = v[0] * NS;
        float2v e0 = tab[qb + v[1]];
        float2v e1 = tab[qb + v[2]];
        float2v e2 = tab[qb + v[3]];
        float2v e3 = tab[qb + v[4]];

        float S = (e0.x + e1.x) + (e2.x + e3.x);
        float T = (e0.y + e1.y) + (e2.y + e3.y);
        float invS = __builtin_amdgcn_rcpf(S);

        float ent = LN2 * __builtin_amdgcn_logf(S) - T * invS;   // -sum p log p
        float z   = -rate * (ent - mid);
        float rt  = upper * __builtin_amdgcn_rcpf(
                        1.0f + __builtin_amdgcn_exp2f(z * LOG2E));

        float4v p;
        p.x = e0.x * invS;
        p.y = e1.x * invS;
        p.z = e2.x * invS;
        p.w = e3.x * invS;
        *reinterpret_cast<float4v*>(out + (size_t)row * 4) = p;
        out[(size_t)nrows * 4 + row] = rt;
    }
}

extern "C" void kernel_launch(void* const* d_in, const int* in_sizes, int n_in,
                              void* d_out, int out_size, void* d_ws, size_t ws_size,
                              hipStream_t stream) {
    const int*   idx     = (const int*)  d_in[0];
    const float* percept = (const float*)d_in[1];
    const float* w       = (const float*)d_in[2];
    const float* rho     = (const float*)d_in[3];
    const float* beta    = (const float*)d_in[4];
    const float* tau     = (const float*)d_in[5];
    const float* gamma   = (const float*)d_in[6];
    const float* upper   = (const float*)d_in[7];
    const float* mid     = (const float*)d_in[8];
    const float* rate    = (const float*)d_in[9];
    float* out = (float*)d_out;

    const int nrows = in_sizes[0] / 5;
    const int NT    = (nrows + 1) / 2;      // 2 rows per thread, split-chunk
    const int block = 256;
    const int grid  = (NT + block - 1) / block;   // 4096 blocks at B=2M

    rank_rt_kernel<<<grid, block, 0, stream>>>(
        idx, percept, w, rho, beta, tau, gamma, upper, mid, rate, out, nrows, NT);
}